// Round 14
// baseline (227.193 us; speedup 1.0000x reference)
//
#include <hip/hip_runtime.h>

typedef __bf16 bf16x8 __attribute__((ext_vector_type(8)));
typedef float  f32x4  __attribute__((ext_vector_type(4)));
typedef float  f32x2  __attribute__((ext_vector_type(2)));
typedef unsigned short u16;
typedef unsigned int   u32;
typedef long long      i64;

#define BSH   7                   // nodes per dst-bucket = 128
#define SRCSH 13                  // src tile = 8192 nodes (2 MB of T)
#define BCAP  512                 // max edges per (dst-bucket, src-tile) sub-bucket
#define NPB   256                 // partition blocks
#define MAXB2 4096                // max 2D buckets (LDS histogram size)

__device__ __forceinline__ float b2f(u16 x){ return __uint_as_float(((u32)x) << 16); }
__device__ __forceinline__ u16 f2b(float x){
  u32 u = __float_as_uint(x);
  return (u16)((u + 0x7FFFu + ((u >> 16) & 1u)) >> 16);
}

// accumulate a packed bf16 pair into a packed f32x2 accumulator (exact).
__device__ __forceinline__ void d2acc(u32 pair, f32x2& a){
  f32x2 t;
  t.x = __uint_as_float(pair << 16);
  t.y = __uint_as_float(pair & 0xFFFF0000u);
  a += t;
}
__device__ __forceinline__ void acc8(uint4 q, f32x2* a){
  d2acc(q.x, a[0]); d2acc(q.y, a[1]); d2acc(q.z, a[2]); d2acc(q.w, a[3]);
}

// flags[0] = 1 if float tensors are f32 on device (else bf16)
// flags[1] = 1 if edge_index is int64 on device (else int32)
// Also zeroes T's pad row (row n, 128 u16).
__global__ __launch_bounds__(256) void k_detect(const u16* __restrict__ x,
                                                const u32* __restrict__ ei,
                                                int* __restrict__ flags,
                                                u16* __restrict__ T, int n){
  __shared__ int sh[2];
  int t = threadIdx.x;
  if (t < 2) sh[t] = 0;
  __syncthreads();
  int sane = 0;
  for (int i = t; i < 4096; i += 256){
    u16 u = x[i]; u32 e = (u >> 7) & 0xFFu;
    if (u == 0 || (e >= 0x70u && e <= 0x8Fu)) sane++;
  }
  int nz = 0;
  for (int i = t; i < 1024; i += 256)
    if (ei[2*i + 1] != 0u) nz++;
  atomicAdd(&sh[0], sane);
  atomicAdd(&sh[1], nz);
  if (t < 128) T[(size_t)n*128 + t] = 0;   // zero pad-row
  __syncthreads();
  if (t == 0){
    flags[0] = (sh[0] < 3500) ? 1 : 0;
    flags[1] = (sh[1] == 0) ? 1 : 0;
  }
}

__device__ __forceinline__ int ld_idx(const void* ei, long long j, int is64){
  return is64 ? (int)((const i64*)ei)[j] : ((const int*)ei)[j];
}
// load 8 consecutive float params (f32 or bf16) starting at elem base (mult of 8)
__device__ __forceinline__ void ld8(const void* p, int base, int f, float* o){
  if (f){
    float4 a = *(const float4*)((const float*)p + base);
    float4 b = *(const float4*)((const float*)p + base + 4);
    o[0]=a.x; o[1]=a.y; o[2]=a.z; o[3]=a.w;
    o[4]=b.x; o[5]=b.y; o[6]=b.z; o[7]=b.w;
  } else {
    uint4 q = *(const uint4*)((const u16*)p + base);
    o[0]=b2f((u16)(q.x&0xffff)); o[1]=b2f((u16)(q.x>>16));
    o[2]=b2f((u16)(q.y&0xffff)); o[3]=b2f((u16)(q.y>>16));
    o[4]=b2f((u16)(q.z&0xffff)); o[5]=b2f((u16)(q.z>>16));
    o[6]=b2f((u16)(q.w&0xffff)); o[7]=b2f((u16)(q.w>>16));
  }
}

// ---- atomic-free 3-phase edge partition over 2D (dst-bucket, src-tile) keys ----
__global__ __launch_bounds__(256) void k_partA(const void* __restrict__ ei, int E, int n,
                                               int* __restrict__ cntmat,
                                               const int* __restrict__ flags,
                                               int NT, int nb2){
  __shared__ int cnt[MAXB2];
  int t = threadIdx.x;
  int is64 = flags[1];
  for (int i = t; i < nb2; i += 256) cnt[i] = 0;
  __syncthreads();
  long long R = ((long long)E + NPB - 1) / NPB;
  long long lo = (long long)blockIdx.x * R;
  long long hi = lo + R; if (hi > E) hi = E;
  for (long long e = lo + t; e < hi; e += 256){
    int d = ld_idx(ei, (long long)E + e, is64);
    int s = ld_idx(ei, e, is64);
    if ((unsigned)d < (unsigned)n && (unsigned)s < (unsigned)n){
      int key = ((unsigned)d >> BSH)*NT + ((unsigned)s >> SRCSH);
      atomicAdd(&cnt[key], 1);
    }
  }
  __syncthreads();
  for (int b = t; b < nb2; b += 256)
    cntmat[(size_t)b*NPB + blockIdx.x] = cnt[b];
}

__global__ __launch_bounds__(NPB) void k_scanBK(const int* __restrict__ cntmat,
                                                int* __restrict__ basemat,
                                                int* __restrict__ bcnt){
  __shared__ int sh[NPB];
  int b = blockIdx.x, t = threadIdx.x;
  int v = cntmat[(size_t)b*NPB + t];
  sh[t] = v; __syncthreads();
  for (int off = 1; off < NPB; off <<= 1){
    int u = 0; if (t >= off) u = sh[t - off];
    __syncthreads(); sh[t] += u; __syncthreads();
  }
  basemat[(size_t)b*NPB + t] = sh[t] - v;
  if (t == NPB-1) bcnt[b] = sh[t];
}

__global__ __launch_bounds__(256) void k_partC(const void* __restrict__ ei, int E, int n,
                                               const int* __restrict__ basemat,
                                               u32* __restrict__ ebuf,
                                               const int* __restrict__ flags,
                                               int NT, int nb2){
  __shared__ int cur[MAXB2];
  int t = threadIdx.x;
  int is64 = flags[1];
  for (int b = t; b < nb2; b += 256) cur[b] = basemat[(size_t)b*NPB + blockIdx.x];
  __syncthreads();
  long long R = ((long long)E + NPB - 1) / NPB;
  long long lo = (long long)blockIdx.x * R;
  long long hi = lo + R; if (hi > E) hi = E;
  for (long long e = lo + t; e < hi; e += 256){
    int d = ld_idx(ei, (long long)E + e, is64);
    int s = ld_idx(ei, e, is64);
    if ((unsigned)d < (unsigned)n && (unsigned)s < (unsigned)n){
      int key = ((unsigned)d >> BSH)*NT + ((unsigned)s >> SRCSH);
      int p = atomicAdd(&cur[key], 1);
      if (p < BCAP) ebuf[(size_t)key*BCAP + p] = (u32)s | ((u32)(d & ((1<<BSH)-1)) << 17);
    }
  }
}

// per-dst-bucket histogram over its NT sub-buckets -> deg
__global__ __launch_bounds__(256) void k_bdeg(const int* __restrict__ bcnt,
                                              const u32* __restrict__ ebuf,
                                              int* __restrict__ deg, int n, int NT){
  __shared__ int cnt[1<<BSH];
  int b = blockIdx.x, t = threadIdx.x;
  if (t < (1<<BSH)) cnt[t] = 0;
  __syncthreads();
  for (int st = 0; st < NT; ++st){
    int key = b*NT + st;
    int m = bcnt[key]; if (m > BCAP) m = BCAP;
    const u32* eb = ebuf + (size_t)key*BCAP;
    for (int i = t; i < m; i += 256)
      atomicAdd(&cnt[eb[i] >> 17], 1);
  }
  __syncthreads();
  if (t < (1<<BSH)){
    int node = (b << BSH) + t;
    if (node < n) deg[node] = cnt[t];
  }
}

// ---- hierarchical scan over PADDED degrees (rows padded to multiple of 4) ----
__global__ __launch_bounds__(256) void k_scanA(const int* __restrict__ deg, int n,
                                               int* __restrict__ bsum){
  __shared__ int sh[256];
  int t = threadIdx.x;
  int base = blockIdx.x*1024 + t*4;
  int s = 0;
  #pragma unroll
  for (int i = 0; i < 4; ++i){
    int idx = base + i;
    if (idx < n) s += (deg[idx] + 3) & ~3;
  }
  sh[t] = s; __syncthreads();
  for (int off = 128; off; off >>= 1){
    if (t < off) sh[t] += sh[t + off];
    __syncthreads();
  }
  if (t == 0) bsum[blockIdx.x] = sh[0];
}

__global__ __launch_bounds__(256) void k_scanB(int* __restrict__ bsum, int nB,
                                               int* __restrict__ rowptr, int n){
  __shared__ int sh[256];
  int t = threadIdx.x;
  int v = (t < nB) ? bsum[t] : 0;
  sh[t] = v; __syncthreads();
  for (int off = 1; off < 256; off <<= 1){
    int u = 0; if (t >= off) u = sh[t - off];
    __syncthreads(); sh[t] += u; __syncthreads();
  }
  if (t < nB) bsum[t] = sh[t] - v;
  if (t == 255) rowptr[n] = sh[255];
}

__global__ __launch_bounds__(256) void k_scanC(const int* __restrict__ deg, int n,
                                               const int* __restrict__ bsum,
                                               int* __restrict__ rowptr,
                                               float* __restrict__ dis){
  __shared__ int sh[256];
  int t = threadIdx.x;
  int base = blockIdx.x*1024 + t*4;
  int d[4]; int s = 0;
  #pragma unroll
  for (int i = 0; i < 4; ++i){
    int idx = base + i;
    d[i] = (idx < n) ? deg[idx] : 0;
    s += (d[i] + 3) & ~3;
  }
  sh[t] = s; __syncthreads();
  for (int off = 1; off < 256; off <<= 1){
    int u = 0; if (t >= off) u = sh[t - off];
    __syncthreads(); sh[t] += u; __syncthreads();
  }
  int run = bsum[blockIdx.x] + sh[t] - s;
  #pragma unroll
  for (int i = 0; i < 4; ++i){
    int idx = base + i;
    if (idx < n){
      rowptr[idx] = run; run += (d[i] + 3) & ~3;
      dis[idx] = rsqrtf((float)(d[i] + 1));
    }
  }
}

// CSR fill, src-tile-ordered within each row (barrier between tiles).
// colx = PRE-SCALED byte offsets (src*256); pad entries -> zero row.
__global__ __launch_bounds__(256) void k_bfill(const int* __restrict__ bcnt,
                                               const u32* __restrict__ ebuf,
                                               const int* __restrict__ rowptr,
                                               int* __restrict__ colx, int n, int NT){
  __shared__ int cur[1<<BSH];
  int b = blockIdx.x, t = threadIdx.x;
  int node = (b << BSH) + (t & ((1<<BSH)-1));
  if (t < (1<<BSH))
    cur[t] = (node < n) ? rowptr[node] : 0;
  __syncthreads();
  for (int st = 0; st < NT; ++st){
    int key = b*NT + st;
    int m = bcnt[key]; if (m > BCAP) m = BCAP;
    const u32* eb = ebuf + (size_t)key*BCAP;
    for (int i = t; i < m; i += 256){
      u32 e = eb[i];
      int p = atomicAdd(&cur[e >> 17], 1);
      colx[p] = (int)((e & 0x1FFFFu) << 8);
    }
    __syncthreads();   // keep rows sorted by src tile
  }
  if (t < (1<<BSH) && node < n){
    int zoff = n << 8;
    int end = rowptr[node + 1];
    for (int p = cur[t]; p < end; ++p) colx[p] = zoff;
  }
}

// pre-shuffle all three W (128x128) into MFMA B-fragment order. 96 blocks.
__global__ __launch_bounds__(64) void k_shufW3(const void* __restrict__ W1,
                                               const void* __restrict__ W2,
                                               const void* __restrict__ W3,
                                               u16* __restrict__ Ws,
                                               const int* __restrict__ flags){
  int f = flags[0];
  int sel = blockIdx.x >> 5;
  const void* W = (sel == 0) ? W1 : (sel == 1) ? W2 : W3;
  u16* Wo = Ws + (size_t)sel * 128 * 128;
  int bid = blockIdx.x & 31;
  int nt = bid >> 2, kk = bid & 3;
  int l = threadIdx.x;
  int g = l >> 4, mr = l & 15;
  int nn = nt*16 + mr;
  #pragma unroll
  for (int i = 0; i < 8; ++i){
    int k = kk*32 + g*4 + (i & 3) + ((i >> 2) << 4);
    u16 w = f ? f2b(((const float*)W)[k*128 + nn]) : ((const u16*)W)[k*128 + nn];
    Wo[(size_t)(bid*64 + l)*8 + i] = w;
  }
}

// T = (A @ W) * dis[row], bf16 out. One wave per 16-row tile.
__global__ __launch_bounds__(256) void k_gemm(const void* __restrict__ A, int aExt,
    const u16* __restrict__ Ws, const float* __restrict__ dis,
    u16* __restrict__ T, int nTiles, const int* __restrict__ flags)
{
  int wave = threadIdx.x >> 6, lane = threadIdx.x & 63;
  int tile = blockIdx.x*4 + wave;
  if (tile >= nTiles) return;
  int g = lane >> 4, mr = lane & 15;
  int f = aExt ? flags[0] : 0;
  union U8 { ushort4 q[2]; u16 s[8]; bf16x8 b; };
  bf16x8 a[4];
  if (f){
    const float* ap = (const float*)A + (size_t)(tile*16 + mr)*128;
    #pragma unroll
    for (int kk = 0; kk < 4; ++kk){
      float4 p = *(const float4*)(ap + kk*32 + g*4);
      float4 q = *(const float4*)(ap + kk*32 + g*4 + 16);
      U8 u;
      u.s[0]=f2b(p.x); u.s[1]=f2b(p.y); u.s[2]=f2b(p.z); u.s[3]=f2b(p.w);
      u.s[4]=f2b(q.x); u.s[5]=f2b(q.y); u.s[6]=f2b(q.z); u.s[7]=f2b(q.w);
      a[kk] = u.b;
    }
  } else {
    const u16* ap = (const u16*)A + (size_t)(tile*16 + mr)*128;
    #pragma unroll
    for (int kk = 0; kk < 4; ++kk){
      U8 u;
      u.q[0] = *(const ushort4*)(ap + kk*32 + g*4);
      u.q[1] = *(const ushort4*)(ap + kk*32 + g*4 + 16);
      a[kk] = u.b;
    }
  }
  float dj[4];
  #pragma unroll
  for (int j = 0; j < 4; ++j) dj[j] = dis[tile*16 + g*4 + j];
  #pragma unroll
  for (int nt = 0; nt < 8; ++nt){
    f32x4 acc = {0.f,0.f,0.f,0.f};
    #pragma unroll
    for (int kk = 0; kk < 4; ++kk){
      bf16x8 b = *(const bf16x8*)(Ws + (size_t)((nt*4 + kk)*64 + lane)*8);
      acc = __builtin_amdgcn_mfma_f32_16x16x32_bf16(a[kk], b, acc, 0, 0, 0);
    }
    int nn = nt*16 + mr;
    #pragma unroll
    for (int j = 0; j < 4; ++j){
      int row = tile*16 + g*4 + j;
      T[(size_t)row*128 + nn] = f2b(acc[j] * dj[j]);
    }
  }
}

// aggregation + bias + epilogue over bf16 T.
// FOUR nodes per wave (16-lane group per node). Rows padded to x4, src-tile
// sorted -> gathers sweep 2MB tiles of T (L2-resident). 8 rows in flight/group.
template<int MODE>
__global__ __launch_bounds__(256) void k_agg(const u16* __restrict__ T,
    const int* __restrict__ rowptr, const int* __restrict__ colx,
    const float* __restrict__ dis, const void* __restrict__ bias,
    const void* __restrict__ lg, const void* __restrict__ lb,
    void* __restrict__ outA, int n, const int* __restrict__ flags)
{
  int wave = threadIdx.x >> 6, l = threadIdx.x & 63;
  int g = l >> 4, c = l & 15;     // node slot (0..3), dim chunk (8 dims = 16 B)
  int v = blockIdx.x*16 + wave*4 + g;
  bool alive = v < n;
  int vv = alive ? v : (n - 1);
  int f = flags[0];
  const char* Tb = (const char*)T + c*16;

  f32x2 aA[4] = {};
  f32x2 aB[4] = {};
  // self row
  {
    uint4 q = *(const uint4*)(Tb + ((size_t)vv << 8));
    acc8(q, aA);
  }
  int s = rowptr[vv], e = rowptr[vv+1];
  int i = s;
  for (; i + 8 <= e; i += 8){
    uint4 oA = *(const uint4*)(colx + i);
    uint4 oB = *(const uint4*)(colx + i + 4);
    uint4 q0 = *(const uint4*)(Tb + oA.x);
    uint4 q1 = *(const uint4*)(Tb + oA.y);
    uint4 q2 = *(const uint4*)(Tb + oA.z);
    uint4 q3 = *(const uint4*)(Tb + oA.w);
    uint4 q4 = *(const uint4*)(Tb + oB.x);
    uint4 q5 = *(const uint4*)(Tb + oB.y);
    uint4 q6 = *(const uint4*)(Tb + oB.z);
    uint4 q7 = *(const uint4*)(Tb + oB.w);
    acc8(q0, aA); acc8(q1, aB); acc8(q2, aA); acc8(q3, aB);
    acc8(q4, aA); acc8(q5, aB); acc8(q6, aA); acc8(q7, aB);
  }
  if (i < e){   // exactly 4 remain (rows are multiples of 4)
    uint4 o = *(const uint4*)(colx + i);
    uint4 q0 = *(const uint4*)(Tb + o.x);
    uint4 q1 = *(const uint4*)(Tb + o.y);
    uint4 q2 = *(const uint4*)(Tb + o.z);
    uint4 q3 = *(const uint4*)(Tb + o.w);
    acc8(q0, aA); acc8(q1, aB); acc8(q2, aA); acc8(q3, aB);
  }

  // merge dual banks in-lane
  float acc[8];
  #pragma unroll
  for (int k = 0; k < 4; ++k){
    acc[2*k]   = aA[k].x + aB[k].x;
    acc[2*k+1] = aA[k].y + aB[k].y;
  }
  float sc = dis[vv];
  float bv[8]; ld8(bias, c*8, f, bv);
  float x[8];
  #pragma unroll
  for (int k = 0; k < 8; ++k) x[k] = fmaf(acc[k], sc, bv[k]);

  if (MODE == 0){
    #pragma unroll
    for (int k = 0; k < 8; ++k) x[k] = fmaxf(x[k], 0.f);
    float sum = 0.f;
    #pragma unroll
    for (int k = 0; k < 8; ++k) sum += x[k];
    #pragma unroll
    for (int off = 8; off; off >>= 1) sum += __shfl_xor(sum, off);  // within 16 lanes
    float mu = sum * (1.f/128.f);
    float vs = 0.f;
    #pragma unroll
    for (int k = 0; k < 8; ++k){ float d = x[k] - mu; vs += d*d; }
    #pragma unroll
    for (int off = 8; off; off >>= 1) vs += __shfl_xor(vs, off);
    float inv = rsqrtf(vs*(1.f/128.f) + 1e-5f);
    float gv[8], bvv[8];
    ld8(lg, c*8, f, gv); ld8(lb, c*8, f, bvv);
    if (alive){
      uint4 w;
      float y0,y1;
      y0 = (x[0]-mu)*inv*gv[0] + bvv[0]; y1 = (x[1]-mu)*inv*gv[1] + bvv[1];
      w.x = (u32)f2b(y0) | ((u32)f2b(y1) << 16);
      y0 = (x[2]-mu)*inv*gv[2] + bvv[2]; y1 = (x[3]-mu)*inv*gv[3] + bvv[3];
      w.y = (u32)f2b(y0) | ((u32)f2b(y1) << 16);
      y0 = (x[4]-mu)*inv*gv[4] + bvv[4]; y1 = (x[5]-mu)*inv*gv[5] + bvv[5];
      w.z = (u32)f2b(y0) | ((u32)f2b(y1) << 16);
      y0 = (x[6]-mu)*inv*gv[6] + bvv[6]; y1 = (x[7]-mu)*inv*gv[7] + bvv[7];
      w.w = (u32)f2b(y0) | ((u32)f2b(y1) << 16);
      *(uint4*)((u16*)outA + (size_t)v*128 + c*8) = w;
    }
  } else {
    if (alive){
      if (f){
        float* oa = (float*)outA + (size_t)v*128 + c*8;
        *(float4*)(oa)     = make_float4(x[0], x[1], x[2], x[3]);
        *(float4*)(oa + 4) = make_float4(x[4], x[5], x[6], x[7]);
      } else {
        uint4 w;
        w.x = (u32)f2b(x[0]) | ((u32)f2b(x[1]) << 16);
        w.y = (u32)f2b(x[2]) | ((u32)f2b(x[3]) << 16);
        w.z = (u32)f2b(x[4]) | ((u32)f2b(x[5]) << 16);
        w.w = (u32)f2b(x[6]) | ((u32)f2b(x[7]) << 16);
        *(uint4*)((u16*)outA + (size_t)v*128 + c*8) = w;
      }
    }
  }
}

// collapse post_mp: Wc = mpW1 @ mpW2 (128x40 f32), bc = mpb1 @ mpW2 + mpb2
__global__ __launch_bounds__(128) void k_wc(const void* __restrict__ mpW1, const void* __restrict__ mpb1,
    const void* __restrict__ mpW2, const void* __restrict__ mpb2,
    float* __restrict__ Wc, float* __restrict__ bc, const int* __restrict__ flags)
{
  int f = flags[0];
  int c = blockIdx.x;   // 0..39
  int k = threadIdx.x;  // 0..127
  float acc = 0.f;
  if (f){
    const float* A  = (const float*)mpW1 + (size_t)k*128;
    const float* B2 = (const float*)mpW2;
    #pragma unroll 8
    for (int j = 0; j < 128; ++j) acc = fmaf(A[j], B2[j*40 + c], acc);
    if (k == 0){
      const float* b1p = (const float*)mpb1;
      float b = ((const float*)mpb2)[c];
      #pragma unroll 8
      for (int j = 0; j < 128; ++j) b = fmaf(b1p[j], B2[j*40 + c], b);
      bc[c] = b;
    }
  } else {
    const u16* A  = (const u16*)mpW1 + (size_t)k*128;
    const u16* B2 = (const u16*)mpW2;
    #pragma unroll 8
    for (int j = 0; j < 128; ++j) acc = fmaf(b2f(A[j]), b2f(B2[j*40 + c]), acc);
    if (k == 0){
      const u16* b1p = (const u16*)mpb1;
      float b = b2f(((const u16*)mpb2)[c]);
      #pragma unroll 8
      for (int j = 0; j < 128; ++j) b = fmaf(b2f(b1p[j]), b2f(B2[j*40 + c]), b);
      bc[c] = b;
    }
  }
  Wc[k*40 + c] = acc;
}

// shuffle Wc (128x40 f32) -> bf16 B-frags padded to 48 cols. 12 frags.
__global__ __launch_bounds__(64) void k_shufWc(const float* __restrict__ Wc, u16* __restrict__ Wcs){
  int bid = blockIdx.x;          // 0..11
  int nt = bid >> 2, kk = bid & 3;
  int l = threadIdx.x;
  int g = l >> 4, mr = l & 15;
  int nn = nt*16 + mr;
  #pragma unroll
  for (int i = 0; i < 8; ++i){
    int k = kk*32 + g*4 + (i & 3) + ((i >> 2) << 4);
    Wcs[(size_t)(bid*64 + l)*8 + i] = (nn < 40) ? f2b(Wc[k*40 + nn]) : (u16)0;
  }
}

// logits via MFMA + in-register log_softmax. One wave per 16-node tile.
__global__ __launch_bounds__(256) void k_logitsM(const u16* __restrict__ Wcs,
    const float* __restrict__ bc, void* __restrict__ dout, int n,
    const int* __restrict__ flags)
{
  int wave = threadIdx.x >> 6, lane = threadIdx.x & 63;
  int tile = blockIdx.x*4 + wave;
  int nTiles = n >> 4;
  if (tile >= nTiles) return;
  int f = flags[0];
  int g = lane >> 4, mr = lane & 15;
  union U8 { ushort4 q[2]; u16 s[8]; bf16x8 b; };
  bf16x8 a[4];
  if (f){
    const float* ap = (const float*)dout + (size_t)(tile*16 + mr)*128;
    #pragma unroll
    for (int kk = 0; kk < 4; ++kk){
      float4 p = *(const float4*)(ap + kk*32 + g*4);
      float4 q = *(const float4*)(ap + kk*32 + g*4 + 16);
      U8 u;
      u.s[0]=f2b(fmaxf(p.x,0.f)); u.s[1]=f2b(fmaxf(p.y,0.f));
      u.s[2]=f2b(fmaxf(p.z,0.f)); u.s[3]=f2b(fmaxf(p.w,0.f));
      u.s[4]=f2b(fmaxf(q.x,0.f)); u.s[5]=f2b(fmaxf(q.y,0.f));
      u.s[6]=f2b(fmaxf(q.z,0.f)); u.s[7]=f2b(fmaxf(q.w,0.f));
      a[kk] = u.b;
    }
  } else {
    const u16* ap = (const u16*)dout + (size_t)(tile*16 + mr)*128;
    #pragma unroll
    for (int kk = 0; kk < 4; ++kk){
      U8 u;
      u.q[0] = *(const ushort4*)(ap + kk*32 + g*4);
      u.q[1] = *(const ushort4*)(ap + kk*32 + g*4 + 16);
      #pragma unroll
      for (int i = 0; i < 8; ++i) u.s[i] = (u.s[i] & 0x8000u) ? (u16)0 : u.s[i];  // relu
      a[kk] = u.b;
    }
  }
  f32x4 acc[3];
  #pragma unroll
  for (int nt = 0; nt < 3; ++nt){
    f32x4 c4 = {0.f,0.f,0.f,0.f};
    #pragma unroll
    for (int kk = 0; kk < 4; ++kk){
      bf16x8 b = *(const bf16x8*)(Wcs + (size_t)((nt*4 + kk)*64 + lane)*8);
      c4 = __builtin_amdgcn_mfma_f32_16x16x32_bf16(a[kk], b, c4, 0, 0, 0);
    }
    acc[nt] = c4;
  }
  float bcv[3]; bool valid[3];
  #pragma unroll
  for (int nt = 0; nt < 3; ++nt){
    int c = nt*16 + mr;
    valid[nt] = (c < 40);
    bcv[nt] = valid[nt] ? bc[c] : 0.f;
  }
  float* of = (float*)dout + (size_t)n*128;
  u16*  ob = (u16*) dout + (size_t)n*128;
  #pragma unroll
  for (int j = 0; j < 4; ++j){
    float l0 = valid[0] ? acc[0][j] + bcv[0] : -3.0e38f;
    float l1 = valid[1] ? acc[1][j] + bcv[1] : -3.0e38f;
    float l2 = valid[2] ? acc[2][j] + bcv[2] : -3.0e38f;
    float m = fmaxf(l0, fmaxf(l1, l2));
    #pragma unroll
    for (int off = 8; off; off >>= 1) m = fmaxf(m, __shfl_xor(m, off));
    float ssum = (valid[0] ? expf(l0 - m) : 0.f)
               + (valid[1] ? expf(l1 - m) : 0.f)
               + (valid[2] ? expf(l2 - m) : 0.f);
    #pragma unroll
    for (int off = 8; off; off >>= 1) ssum += __shfl_xor(ssum, off);
    float lgs = m + logf(ssum);
    int node = tile*16 + g*4 + j;
    #pragma unroll
    for (int nt = 0; nt < 3; ++nt){
      if (valid[nt]){
        int c = nt*16 + mr;
        float r = (nt==0 ? l0 : (nt==1 ? l1 : l2)) - lgs;
        if (f) of[(size_t)node*40 + c] = r;
        else   ob[(size_t)node*40 + c] = f2b(r);
      }
    }
  }
}

extern "C" void kernel_launch(void* const* d_in, const int* in_sizes, int n_in,
                              void* d_out, int out_size, void* d_ws, size_t ws_size,
                              hipStream_t stream)
{
  const int n = in_sizes[0] / 128;
  const int E = in_sizes[1] / 2;

  const void* x    = d_in[0];
  const void* ei   = d_in[1];
  const void* W1   = d_in[2];
  const void* b1   = d_in[3];
  const void* W2   = d_in[4];
  const void* b2   = d_in[5];
  const void* W3   = d_in[6];
  const void* b3   = d_in[7];
  const void* ln1g = d_in[8];
  const void* ln1b = d_in[9];
  const void* ln2g = d_in[10];
  const void* ln2b = d_in[11];
  const void* mpW1 = d_in[12];
  const void* mpb1 = d_in[13];
  const void* mpW2 = d_in[14];
  const void* mpb2 = d_in[15];

  u16* Hbuf = (u16*)d_out;  // d_out emb region doubles as H buffer until layer 3

  char* w = (char*)d_ws;
  size_t off = 0;
  auto alloc = [&](size_t bytes)->char*{
    char* p = w + off; off = (off + bytes + 255) & ~(size_t)255; return p;
  };
  const int nbuk = (n + (1<<BSH) - 1) >> BSH;
  int NT = (n + (1<<SRCSH) - 1) >> SRCSH;           // src tiles (7 at n=50000)
  int nb2 = nbuk * NT;                              // 2737 2D buckets
  if (nb2 > MAXB2){ NT = MAXB2 / nbuk; nb2 = nbuk * NT; }  // safety clamp

  int*   flags = (int*)  alloc(256);
  float* dis   = (float*)alloc((size_t)n*4);
  int*   deg   = (int*)  alloc((size_t)n*4);
  int*   rowp  = (int*)  alloc((size_t)(n+1)*4);
  int*   bsum  = (int*)  alloc(1024);
  int*   bcnt  = (int*)  alloc((size_t)nb2*4);
  int*   cntm  = (int*)  alloc((size_t)nb2*NPB*4);
  int*   basem = (int*)  alloc((size_t)nb2*NPB*4);
  u32*   ebuf  = (u32*)  alloc((size_t)nb2*BCAP*4);
  int*   colx  = (int*)  alloc(((size_t)E + 4*(size_t)n)*4 + 256);
  u16*   T     = (u16*)  alloc((size_t)(n+1)*128*2);   // +1 zero pad-row
  u16*   Ws    = (u16*)  alloc((size_t)3*128*128*2);   // 3 layers pre-shuffled
  float* Wc    = (float*)alloc((size_t)128*40*4);
  float* bc    = (float*)alloc((size_t)64*4);
  u16*   Wcs   = (u16*)  alloc((size_t)12*64*8*2);

  int nB = (n + 1023) / 1024;

  k_detect<<<1, 256, 0, stream>>>((const u16*)x, (const u32*)ei, flags, T, n);
  k_shufW3<<<96, 64, 0, stream>>>(W1, W2, W3, Ws, flags);
  k_partA <<<NPB, 256, 0, stream>>>(ei, E, n, cntm, flags, NT, nb2);
  k_scanBK<<<nb2, NPB, 0, stream>>>(cntm, basem, bcnt);
  k_partC <<<NPB, 256, 0, stream>>>(ei, E, n, basem, ebuf, flags, NT, nb2);
  k_bdeg  <<<nbuk, 256, 0, stream>>>(bcnt, ebuf, deg, n, NT);
  k_scanA <<<nB, 256, 0, stream>>>(deg, n, bsum);
  k_scanB <<<1, 256, 0, stream>>>(bsum, nB, rowp, n);
  k_scanC <<<nB, 256, 0, stream>>>(deg, n, bsum, rowp, dis);
  k_bfill <<<nbuk, 256, 0, stream>>>(bcnt, ebuf, rowp, colx, n, NT);
  k_wc    <<<40, 128, 0, stream>>>(mpW1, mpb1, mpW2, mpb2, Wc, bc, flags);
  k_shufWc<<<12, 64, 0, stream>>>(Wc, Wcs);

  int nTiles = (n + 15) / 16;
  int gG = (nTiles + 3) / 4;
  int gA = (n + 15) / 16;    // 16 nodes per block (4 per wave)

  // layer 0
  k_gemm <<<gG, 256, 0, stream>>>(x, 1, Ws, dis, T, nTiles, flags);
  k_agg<0><<<gA, 256, 0, stream>>>(T, rowp, colx, dis, b1, ln1g, ln1b, Hbuf, n, flags);
  // layer 1
  k_gemm <<<gG, 256, 0, stream>>>(Hbuf, 0, Ws + (size_t)128*128, dis, T, nTiles, flags);
  k_agg<0><<<gA, 256, 0, stream>>>(T, rowp, colx, dis, b2, ln2g, ln2b, Hbuf, n, flags);
  // layer 2: emb -> d_out
  k_gemm <<<gG, 256, 0, stream>>>(Hbuf, 0, Ws + (size_t)2*128*128, dis, T, nTiles, flags);
  k_agg<1><<<gA, 256, 0, stream>>>(T, rowp, colx, dis, b3, nullptr, nullptr, d_out, n, flags);
  // post_mp collapsed + log_softmax (MFMA)
  k_logitsM<<<gG, 256, 0, stream>>>(Wcs, bc, d_out, n, flags);
}

// Round 15
// 206.245 us; speedup vs baseline: 1.1016x; 1.1016x over previous
//
#include <hip/hip_runtime.h>

typedef __bf16 bf16x8 __attribute__((ext_vector_type(8)));
typedef float  f32x4  __attribute__((ext_vector_type(4)));
typedef float  f32x2  __attribute__((ext_vector_type(2)));
typedef unsigned short u16;
typedef unsigned int   u32;
typedef long long      i64;

#define BSH  7                    // nodes per bucket = 128
#define BCAP 4096                 // max edges per bucket (mean ~2045)
#define NPB  256                  // partition blocks

__device__ __forceinline__ float b2f(u16 x){ return __uint_as_float(((u32)x) << 16); }
__device__ __forceinline__ u16 f2b(float x){
  u32 u = __float_as_uint(x);
  return (u16)((u + 0x7FFFu + ((u >> 16) & 1u)) >> 16);
}

// accumulate a packed bf16 pair into a packed f32x2 accumulator (exact).
__device__ __forceinline__ void d2acc(u32 pair, f32x2& a){
  f32x2 t;
  t.x = __uint_as_float(pair << 16);
  t.y = __uint_as_float(pair & 0xFFFF0000u);
  a += t;
}
__device__ __forceinline__ void acc8(uint4 q, f32x2* a){
  d2acc(q.x, a[0]); d2acc(q.y, a[1]); d2acc(q.z, a[2]); d2acc(q.w, a[3]);
}

// flags[0] = 1 if float tensors are f32 on device (else bf16)
// flags[1] = 1 if edge_index is int64 on device (else int32)
// Also zeroes T's pad row (row n, 128 u16).
__global__ __launch_bounds__(256) void k_detect(const u16* __restrict__ x,
                                                const u32* __restrict__ ei,
                                                int* __restrict__ flags,
                                                u16* __restrict__ T, int n){
  __shared__ int sh[2];
  int t = threadIdx.x;
  if (t < 2) sh[t] = 0;
  __syncthreads();
  int sane = 0;
  for (int i = t; i < 4096; i += 256){
    u16 u = x[i]; u32 e = (u >> 7) & 0xFFu;
    if (u == 0 || (e >= 0x70u && e <= 0x8Fu)) sane++;
  }
  int nz = 0;
  for (int i = t; i < 1024; i += 256)
    if (ei[2*i + 1] != 0u) nz++;
  atomicAdd(&sh[0], sane);
  atomicAdd(&sh[1], nz);
  if (t < 128) T[(size_t)n*128 + t] = 0;   // zero pad-row
  __syncthreads();
  if (t == 0){
    flags[0] = (sh[0] < 3500) ? 1 : 0;
    flags[1] = (sh[1] == 0) ? 1 : 0;
  }
}

__device__ __forceinline__ int ld_idx(const void* ei, long long j, int is64){
  return is64 ? (int)((const i64*)ei)[j] : ((const int*)ei)[j];
}
// load 8 consecutive float params (f32 or bf16) starting at elem base (mult of 8)
__device__ __forceinline__ void ld8(const void* p, int base, int f, float* o){
  if (f){
    float4 a = *(const float4*)((const float*)p + base);
    float4 b = *(const float4*)((const float*)p + base + 4);
    o[0]=a.x; o[1]=a.y; o[2]=a.z; o[3]=a.w;
    o[4]=b.x; o[5]=b.y; o[6]=b.z; o[7]=b.w;
  } else {
    uint4 q = *(const uint4*)((const u16*)p + base);
    o[0]=b2f((u16)(q.x&0xffff)); o[1]=b2f((u16)(q.x>>16));
    o[2]=b2f((u16)(q.y&0xffff)); o[3]=b2f((u16)(q.y>>16));
    o[4]=b2f((u16)(q.z&0xffff)); o[5]=b2f((u16)(q.z>>16));
    o[6]=b2f((u16)(q.w&0xffff)); o[7]=b2f((u16)(q.w>>16));
  }
}

// ---- atomic-free 3-phase edge partition (1D dst-buckets) ----
__global__ __launch_bounds__(256) void k_partA(const void* __restrict__ ei, int E, int n,
                                               int* __restrict__ cntmat,
                                               const int* __restrict__ flags, int nbuk){
  __shared__ int cnt[512];
  int t = threadIdx.x;
  int is64 = flags[1];
  for (int i = t; i < 512; i += 256) cnt[i] = 0;
  __syncthreads();
  long long R = ((long long)E + NPB - 1) / NPB;
  long long lo = (long long)blockIdx.x * R;
  long long hi = lo + R; if (hi > E) hi = E;
  for (long long e = lo + t; e < hi; e += 256){
    int d = ld_idx(ei, (long long)E + e, is64);
    if ((unsigned)d < (unsigned)n) atomicAdd(&cnt[(unsigned)d >> BSH], 1);
  }
  __syncthreads();
  for (int b = t; b < nbuk; b += 256)
    cntmat[(size_t)b*NPB + blockIdx.x] = cnt[b];
}

__global__ __launch_bounds__(NPB) void k_scanBK(const int* __restrict__ cntmat,
                                                int* __restrict__ basemat,
                                                int* __restrict__ bcnt){
  __shared__ int sh[NPB];
  int b = blockIdx.x, t = threadIdx.x;
  int v = cntmat[(size_t)b*NPB + t];
  sh[t] = v; __syncthreads();
  for (int off = 1; off < NPB; off <<= 1){
    int u = 0; if (t >= off) u = sh[t - off];
    __syncthreads(); sh[t] += u; __syncthreads();
  }
  basemat[(size_t)b*NPB + t] = sh[t] - v;
  if (t == NPB-1) bcnt[b] = sh[t];
}

__global__ __launch_bounds__(256) void k_partC(const void* __restrict__ ei, int E, int n,
                                               const int* __restrict__ basemat,
                                               u32* __restrict__ ebuf,
                                               const int* __restrict__ flags, int nbuk){
  __shared__ int cur[512];
  int t = threadIdx.x;
  int is64 = flags[1];
  for (int i = t; i < 512; i += 256) cur[i] = 0;
  __syncthreads();
  for (int b = t; b < nbuk; b += 256) cur[b] = basemat[(size_t)b*NPB + blockIdx.x];
  __syncthreads();
  long long R = ((long long)E + NPB - 1) / NPB;
  long long lo = (long long)blockIdx.x * R;
  long long hi = lo + R; if (hi > E) hi = E;
  for (long long e = lo + t; e < hi; e += 256){
    int d = ld_idx(ei, (long long)E + e, is64);
    int s = ld_idx(ei, e, is64);
    if ((unsigned)d < (unsigned)n && (unsigned)s < (unsigned)n){
      int b = (unsigned)d >> BSH;
      int p = atomicAdd(&cur[b], 1);
      if (p < BCAP) ebuf[(size_t)b*BCAP + p] = (u32)s | ((u32)(d & ((1<<BSH)-1)) << 17);
    }
  }
}

// per-bucket histogram -> deg, plus per-bucket PADDED degree sum -> bksum
__global__ __launch_bounds__(256) void k_bdeg(const int* __restrict__ bcnt,
                                              const u32* __restrict__ ebuf,
                                              int* __restrict__ deg,
                                              int* __restrict__ bksum, int n){
  __shared__ int cnt[1<<BSH];
  __shared__ int red[1<<BSH];
  int b = blockIdx.x, t = threadIdx.x;
  if (t < (1<<BSH)) cnt[t] = 0;
  __syncthreads();
  int m = bcnt[b]; if (m > BCAP) m = BCAP;
  const u32* eb = ebuf + (size_t)b*BCAP;
  for (int i = t; i < m; i += 256)
    atomicAdd(&cnt[eb[i] >> 17], 1);
  __syncthreads();
  int node = (b << BSH) + t;
  if (t < (1<<BSH)){
    int d = (node < n) ? cnt[t] : 0;
    if (node < n) deg[node] = d;
    red[t] = (d + 3) & ~3;
  }
  __syncthreads();
  for (int off = 64; off; off >>= 1){
    if (t < off) red[t] += red[t + off];
    __syncthreads();
  }
  if (t == 0) bksum[b] = red[0];
}

// single-block exclusive scan of bucket sums -> bkbase; rowp[n] = total
__global__ __launch_bounds__(512) void k_scanBkt(const int* __restrict__ bksum,
                                                 int* __restrict__ bkbase,
                                                 int* __restrict__ rowptr,
                                                 int nbuk, int n){
  __shared__ int sh[512];
  int t = threadIdx.x;
  int v = (t < nbuk) ? bksum[t] : 0;
  sh[t] = v; __syncthreads();
  for (int off = 1; off < 512; off <<= 1){
    int u = 0; if (t >= off) u = sh[t - off];
    __syncthreads(); sh[t] += u; __syncthreads();
  }
  if (t < nbuk) bkbase[t] = sh[t] - v;
  if (t == 511) rowptr[n] = sh[511];
}

// per-bucket: within-bucket scan of padded degs -> rowptr + dis, LDS cursors,
// src scatter (colx = PRE-SCALED byte offsets), pad tails -> zero row.
__global__ __launch_bounds__(256) void k_bfill(const int* __restrict__ bcnt,
                                               const u32* __restrict__ ebuf,
                                               const int* __restrict__ deg,
                                               const int* __restrict__ bkbase,
                                               int* __restrict__ rowptr,
                                               float* __restrict__ dis,
                                               int* __restrict__ colx, int n){
  __shared__ int cur[1<<BSH];
  __shared__ int pdv[1<<BSH];
  __shared__ int base_[1<<BSH];
  int b = blockIdx.x, t = threadIdx.x;
  int node = (b << BSH) + t;          // valid for t<128
  int d = 0, pd = 0;
  if (t < (1<<BSH)){
    d = (node < n) ? deg[node] : 0;
    pd = (d + 3) & ~3;
    pdv[t] = pd;
    if (node < n) dis[node] = rsqrtf((float)(d + 1));
  }
  __syncthreads();
  // exclusive scan over 128 padded degs (Hillis-Steele in LDS)
  if (t < (1<<BSH)) base_[t] = pdv[t];
  __syncthreads();
  for (int off = 1; off < (1<<BSH); off <<= 1){
    int u = 0;
    if (t < (1<<BSH) && t >= off) u = base_[t - off];
    __syncthreads();
    if (t < (1<<BSH)) base_[t] += u;
    __syncthreads();
  }
  if (t < (1<<BSH)){
    int myBase = bkbase[b] + base_[t] - pdv[t];
    if (node < n) rowptr[node] = myBase;
    cur[t] = myBase;
  }
  __syncthreads();
  int m = bcnt[b]; if (m > BCAP) m = BCAP;
  const u32* eb = ebuf + (size_t)b*BCAP;
  for (int i = t; i < m; i += 256){
    u32 e = eb[i];
    int p = atomicAdd(&cur[e >> 17], 1);
    colx[p] = (int)((e & 0x1FFFFu) << 8);
  }
  __syncthreads();
  if (t < (1<<BSH) && node < n){
    int zoff = n << 8;
    int end = (bkbase[b] + base_[t] - pdv[t]) + pd;
    for (int p = cur[t]; p < end; ++p) colx[p] = zoff;
  }
}

// pre-shuffle all three W (128x128) into MFMA B-fragment order. 96 blocks.
__global__ __launch_bounds__(64) void k_shufW3(const void* __restrict__ W1,
                                               const void* __restrict__ W2,
                                               const void* __restrict__ W3,
                                               u16* __restrict__ Ws,
                                               const int* __restrict__ flags){
  int f = flags[0];
  int sel = blockIdx.x >> 5;
  const void* W = (sel == 0) ? W1 : (sel == 1) ? W2 : W3;
  u16* Wo = Ws + (size_t)sel * 128 * 128;
  int bid = blockIdx.x & 31;
  int nt = bid >> 2, kk = bid & 3;
  int l = threadIdx.x;
  int g = l >> 4, mr = l & 15;
  int nn = nt*16 + mr;
  #pragma unroll
  for (int i = 0; i < 8; ++i){
    int k = kk*32 + g*4 + (i & 3) + ((i >> 2) << 4);
    u16 w = f ? f2b(((const float*)W)[k*128 + nn]) : ((const u16*)W)[k*128 + nn];
    Wo[(size_t)(bid*64 + l)*8 + i] = w;
  }
}

// T = (A @ W) * dis[row], bf16 out. One wave per 16-row tile.
__global__ __launch_bounds__(256) void k_gemm(const void* __restrict__ A, int aExt,
    const u16* __restrict__ Ws, const float* __restrict__ dis,
    u16* __restrict__ T, int nTiles, const int* __restrict__ flags)
{
  int wave = threadIdx.x >> 6, lane = threadIdx.x & 63;
  int tile = blockIdx.x*4 + wave;
  if (tile >= nTiles) return;
  int g = lane >> 4, mr = lane & 15;
  int f = aExt ? flags[0] : 0;
  union U8 { ushort4 q[2]; u16 s[8]; bf16x8 b; };
  bf16x8 a[4];
  if (f){
    const float* ap = (const float*)A + (size_t)(tile*16 + mr)*128;
    #pragma unroll
    for (int kk = 0; kk < 4; ++kk){
      float4 p = *(const float4*)(ap + kk*32 + g*4);
      float4 q = *(const float4*)(ap + kk*32 + g*4 + 16);
      U8 u;
      u.s[0]=f2b(p.x); u.s[1]=f2b(p.y); u.s[2]=f2b(p.z); u.s[3]=f2b(p.w);
      u.s[4]=f2b(q.x); u.s[5]=f2b(q.y); u.s[6]=f2b(q.z); u.s[7]=f2b(q.w);
      a[kk] = u.b;
    }
  } else {
    const u16* ap = (const u16*)A + (size_t)(tile*16 + mr)*128;
    #pragma unroll
    for (int kk = 0; kk < 4; ++kk){
      U8 u;
      u.q[0] = *(const ushort4*)(ap + kk*32 + g*4);
      u.q[1] = *(const ushort4*)(ap + kk*32 + g*4 + 16);
      a[kk] = u.b;
    }
  }
  float dj[4];
  #pragma unroll
  for (int j = 0; j < 4; ++j) dj[j] = dis[tile*16 + g*4 + j];
  #pragma unroll
  for (int nt = 0; nt < 8; ++nt){
    f32x4 acc = {0.f,0.f,0.f,0.f};
    #pragma unroll
    for (int kk = 0; kk < 4; ++kk){
      bf16x8 b = *(const bf16x8*)(Ws + (size_t)((nt*4 + kk)*64 + lane)*8);
      acc = __builtin_amdgcn_mfma_f32_16x16x32_bf16(a[kk], b, acc, 0, 0, 0);
    }
    int nn = nt*16 + mr;
    #pragma unroll
    for (int j = 0; j < 4; ++j){
      int row = tile*16 + g*4 + j;
      T[(size_t)row*128 + nn] = f2b(acc[j] * dj[j]);
    }
  }
}

// aggregation + bias + epilogue over bf16 T.
// FOUR nodes per wave (16-lane group per node). Rows padded to x4 ->
// colx read as aligned uint4, zero tail code, 8 rows in flight per group.
template<int MODE>
__global__ __launch_bounds__(256) void k_agg(const u16* __restrict__ T,
    const int* __restrict__ rowptr, const int* __restrict__ colx,
    const float* __restrict__ dis, const void* __restrict__ bias,
    const void* __restrict__ lg, const void* __restrict__ lb,
    void* __restrict__ outA, int n, const int* __restrict__ flags)
{
  int wave = threadIdx.x >> 6, l = threadIdx.x & 63;
  int g = l >> 4, c = l & 15;     // node slot (0..3), dim chunk (8 dims = 16 B)
  int v = blockIdx.x*16 + wave*4 + g;
  bool alive = v < n;
  int vv = alive ? v : (n - 1);
  int f = flags[0];
  const char* Tb = (const char*)T + c*16;

  f32x2 aA[4] = {};
  f32x2 aB[4] = {};
  // self row
  {
    uint4 q = *(const uint4*)(Tb + ((size_t)vv << 8));
    acc8(q, aA);
  }
  int s = rowptr[vv], e = rowptr[vv+1];
  int i = s;
  for (; i + 8 <= e; i += 8){
    uint4 oA = *(const uint4*)(colx + i);
    uint4 oB = *(const uint4*)(colx + i + 4);
    uint4 q0 = *(const uint4*)(Tb + oA.x);
    uint4 q1 = *(const uint4*)(Tb + oA.y);
    uint4 q2 = *(const uint4*)(Tb + oA.z);
    uint4 q3 = *(const uint4*)(Tb + oA.w);
    uint4 q4 = *(const uint4*)(Tb + oB.x);
    uint4 q5 = *(const uint4*)(Tb + oB.y);
    uint4 q6 = *(const uint4*)(Tb + oB.z);
    uint4 q7 = *(const uint4*)(Tb + oB.w);
    acc8(q0, aA); acc8(q1, aB); acc8(q2, aA); acc8(q3, aB);
    acc8(q4, aA); acc8(q5, aB); acc8(q6, aA); acc8(q7, aB);
  }
  if (i < e){   // exactly 4 remain (rows are multiples of 4)
    uint4 o = *(const uint4*)(colx + i);
    uint4 q0 = *(const uint4*)(Tb + o.x);
    uint4 q1 = *(const uint4*)(Tb + o.y);
    uint4 q2 = *(const uint4*)(Tb + o.z);
    uint4 q3 = *(const uint4*)(Tb + o.w);
    acc8(q0, aA); acc8(q1, aB); acc8(q2, aA); acc8(q3, aB);
  }

  // merge dual banks in-lane
  float acc[8];
  #pragma unroll
  for (int k = 0; k < 4; ++k){
    acc[2*k]   = aA[k].x + aB[k].x;
    acc[2*k+1] = aA[k].y + aB[k].y;
  }
  float sc = dis[vv];
  float bv[8]; ld8(bias, c*8, f, bv);
  float x[8];
  #pragma unroll
  for (int k = 0; k < 8; ++k) x[k] = fmaf(acc[k], sc, bv[k]);

  if (MODE == 0){
    #pragma unroll
    for (int k = 0; k < 8; ++k) x[k] = fmaxf(x[k], 0.f);
    float sum = 0.f;
    #pragma unroll
    for (int k = 0; k < 8; ++k) sum += x[k];
    #pragma unroll
    for (int off = 8; off; off >>= 1) sum += __shfl_xor(sum, off);  // within 16 lanes
    float mu = sum * (1.f/128.f);
    float vs = 0.f;
    #pragma unroll
    for (int k = 0; k < 8; ++k){ float d = x[k] - mu; vs += d*d; }
    #pragma unroll
    for (int off = 8; off; off >>= 1) vs += __shfl_xor(vs, off);
    float inv = rsqrtf(vs*(1.f/128.f) + 1e-5f);
    float gv[8], bvv[8];
    ld8(lg, c*8, f, gv); ld8(lb, c*8, f, bvv);
    if (alive){
      uint4 w;
      float y0,y1;
      y0 = (x[0]-mu)*inv*gv[0] + bvv[0]; y1 = (x[1]-mu)*inv*gv[1] + bvv[1];
      w.x = (u32)f2b(y0) | ((u32)f2b(y1) << 16);
      y0 = (x[2]-mu)*inv*gv[2] + bvv[2]; y1 = (x[3]-mu)*inv*gv[3] + bvv[3];
      w.y = (u32)f2b(y0) | ((u32)f2b(y1) << 16);
      y0 = (x[4]-mu)*inv*gv[4] + bvv[4]; y1 = (x[5]-mu)*inv*gv[5] + bvv[5];
      w.z = (u32)f2b(y0) | ((u32)f2b(y1) << 16);
      y0 = (x[6]-mu)*inv*gv[6] + bvv[6]; y1 = (x[7]-mu)*inv*gv[7] + bvv[7];
      w.w = (u32)f2b(y0) | ((u32)f2b(y1) << 16);
      *(uint4*)((u16*)outA + (size_t)v*128 + c*8) = w;
    }
  } else {
    if (alive){
      if (f){
        float* oa = (float*)outA + (size_t)v*128 + c*8;
        *(float4*)(oa)     = make_float4(x[0], x[1], x[2], x[3]);
        *(float4*)(oa + 4) = make_float4(x[4], x[5], x[6], x[7]);
      } else {
        uint4 w;
        w.x = (u32)f2b(x[0]) | ((u32)f2b(x[1]) << 16);
        w.y = (u32)f2b(x[2]) | ((u32)f2b(x[3]) << 16);
        w.z = (u32)f2b(x[4]) | ((u32)f2b(x[5]) << 16);
        w.w = (u32)f2b(x[6]) | ((u32)f2b(x[7]) << 16);
        *(uint4*)((u16*)outA + (size_t)v*128 + c*8) = w;
      }
    }
  }
}

// post_mp collapse with direct scatter into fragment layout:
// block c in 0..47 (cols, 40 real + 8 zero-pad), thread k in 0..127.
// Wcs frag pos: kk=k>>5, rem=k&31, g=(rem&15)>>2, i=((rem>>4)<<2)|(rem&3),
// bid=(c>>4)*4+kk, l=(g<<4)|(c&15).
__global__ __launch_bounds__(128) void k_wc(const void* __restrict__ mpW1, const void* __restrict__ mpb1,
    const void* __restrict__ mpW2, const void* __restrict__ mpb2,
    u16* __restrict__ Wcs, float* __restrict__ bc, const int* __restrict__ flags)
{
  int f = flags[0];
  int c = blockIdx.x;   // 0..47
  int k = threadIdx.x;  // 0..127
  float acc = 0.f;
  if (c < 40){
    if (f){
      const float* A  = (const float*)mpW1 + (size_t)k*128;
      const float* B2 = (const float*)mpW2;
      #pragma unroll 8
      for (int j = 0; j < 128; ++j) acc = fmaf(A[j], B2[j*40 + c], acc);
      if (k == 0){
        const float* b1p = (const float*)mpb1;
        float b = ((const float*)mpb2)[c];
        #pragma unroll 8
        for (int j = 0; j < 128; ++j) b = fmaf(b1p[j], B2[j*40 + c], b);
        bc[c] = b;
      }
    } else {
      const u16* A  = (const u16*)mpW1 + (size_t)k*128;
      const u16* B2 = (const u16*)mpW2;
      #pragma unroll 8
      for (int j = 0; j < 128; ++j) acc = fmaf(b2f(A[j]), b2f(B2[j*40 + c]), acc);
      if (k == 0){
        const u16* b1p = (const u16*)mpb1;
        float b = b2f(((const u16*)mpb2)[c]);
        #pragma unroll 8
        for (int j = 0; j < 128; ++j) b = fmaf(b2f(b1p[j]), b2f(B2[j*40 + c]), b);
        bc[c] = b;
      }
    }
  }
  int kk = k >> 5, rem = k & 31;
  int g = (rem & 15) >> 2;
  int i = ((rem >> 4) << 2) | (rem & 3);
  int bid = (c >> 4)*4 + kk;
  int l = (g << 4) | (c & 15);
  Wcs[(size_t)(bid*64 + l)*8 + i] = (c < 40) ? f2b(acc) : (u16)0;
}

// logits via MFMA + in-register log_softmax. One wave per 16-node tile.
__global__ __launch_bounds__(256) void k_logitsM(const u16* __restrict__ Wcs,
    const float* __restrict__ bc, void* __restrict__ dout, int n,
    const int* __restrict__ flags)
{
  int wave = threadIdx.x >> 6, lane = threadIdx.x & 63;
  int tile = blockIdx.x*4 + wave;
  int nTiles = n >> 4;
  if (tile >= nTiles) return;
  int f = flags[0];
  int g = lane >> 4, mr = lane & 15;
  union U8 { ushort4 q[2]; u16 s[8]; bf16x8 b; };
  bf16x8 a[4];
  if (f){
    const float* ap = (const float*)dout + (size_t)(tile*16 + mr)*128;
    #pragma unroll
    for (int kk = 0; kk < 4; ++kk){
      float4 p = *(const float4*)(ap + kk*32 + g*4);
      float4 q = *(const float4*)(ap + kk*32 + g*4 + 16);
      U8 u;
      u.s[0]=f2b(fmaxf(p.x,0.f)); u.s[1]=f2b(fmaxf(p.y,0.f));
      u.s[2]=f2b(fmaxf(p.z,0.f)); u.s[3]=f2b(fmaxf(p.w,0.f));
      u.s[4]=f2b(fmaxf(q.x,0.f)); u.s[5]=f2b(fmaxf(q.y,0.f));
      u.s[6]=f2b(fmaxf(q.z,0.f)); u.s[7]=f2b(fmaxf(q.w,0.f));
      a[kk] = u.b;
    }
  } else {
    const u16* ap = (const u16*)dout + (size_t)(tile*16 + mr)*128;
    #pragma unroll
    for (int kk = 0; kk < 4; ++kk){
      U8 u;
      u.q[0] = *(const ushort4*)(ap + kk*32 + g*4);
      u.q[1] = *(const ushort4*)(ap + kk*32 + g*4 + 16);
      #pragma unroll
      for (int i = 0; i < 8; ++i) u.s[i] = (u.s[i] & 0x8000u) ? (u16)0 : u.s[i];  // relu
      a[kk] = u.b;
    }
  }
  f32x4 acc[3];
  #pragma unroll
  for (int nt = 0; nt < 3; ++nt){
    f32x4 c4 = {0.f,0.f,0.f,0.f};
    #pragma unroll
    for (int kk = 0; kk < 4; ++kk){
      bf16x8 b = *(const bf16x8*)(Wcs + (size_t)((nt*4 + kk)*64 + lane)*8);
      c4 = __builtin_amdgcn_mfma_f32_16x16x32_bf16(a[kk], b, c4, 0, 0, 0);
    }
    acc[nt] = c4;
  }
  float bcv[3]; bool valid[3];
  #pragma unroll
  for (int nt = 0; nt < 3; ++nt){
    int c = nt*16 + mr;
    valid[nt] = (c < 40);
    bcv[nt] = valid[nt] ? bc[c] : 0.f;
  }
  float* of = (float*)dout + (size_t)n*128;
  u16*  ob = (u16*) dout + (size_t)n*128;
  #pragma unroll
  for (int j = 0; j < 4; ++j){
    float l0 = valid[0] ? acc[0][j] + bcv[0] : -3.0e38f;
    float l1 = valid[1] ? acc[1][j] + bcv[1] : -3.0e38f;
    float l2 = valid[2] ? acc[2][j] + bcv[2] : -3.0e38f;
    float m = fmaxf(l0, fmaxf(l1, l2));
    #pragma unroll
    for (int off = 8; off; off >>= 1) m = fmaxf(m, __shfl_xor(m, off));
    float ssum = (valid[0] ? expf(l0 - m) : 0.f)
               + (valid[1] ? expf(l1 - m) : 0.f)
               + (valid[2] ? expf(l2 - m) : 0.f);
    #pragma unroll
    for (int off = 8; off; off >>= 1) ssum += __shfl_xor(ssum, off);
    float lgs = m + logf(ssum);
    int node = tile*16 + g*4 + j;
    #pragma unroll
    for (int nt = 0; nt < 3; ++nt){
      if (valid[nt]){
        int c = nt*16 + mr;
        float r = (nt==0 ? l0 : (nt==1 ? l1 : l2)) - lgs;
        if (f) of[(size_t)node*40 + c] = r;
        else   ob[(size_t)node*40 + c] = f2b(r);
      }
    }
  }
}

extern "C" void kernel_launch(void* const* d_in, const int* in_sizes, int n_in,
                              void* d_out, int out_size, void* d_ws, size_t ws_size,
                              hipStream_t stream)
{
  const int n = in_sizes[0] / 128;
  const int E = in_sizes[1] / 2;

  const void* x    = d_in[0];
  const void* ei   = d_in[1];
  const void* W1   = d_in[2];
  const void* b1   = d_in[3];
  const void* W2   = d_in[4];
  const void* b2   = d_in[5];
  const void* W3   = d_in[6];
  const void* b3   = d_in[7];
  const void* ln1g = d_in[8];
  const void* ln1b = d_in[9];
  const void* ln2g = d_in[10];
  const void* ln2b = d_in[11];
  const void* mpW1 = d_in[12];
  const void* mpb1 = d_in[13];
  const void* mpW2 = d_in[14];
  const void* mpb2 = d_in[15];

  u16* Hbuf = (u16*)d_out;  // d_out emb region doubles as H buffer until layer 3

  char* w = (char*)d_ws;
  size_t off = 0;
  auto alloc = [&](size_t bytes)->char*{
    char* p = w + off; off = (off + bytes + 255) & ~(size_t)255; return p;
  };
  const int nbuk = (n + (1<<BSH) - 1) >> BSH;

  int*   flags = (int*)  alloc(256);
  float* dis   = (float*)alloc((size_t)n*4);
  int*   deg   = (int*)  alloc((size_t)n*4);
  int*   rowp  = (int*)  alloc((size_t)(n+1)*4);
  int*   bksum = (int*)  alloc((size_t)nbuk*4 + 256);
  int*   bkbase= (int*)  alloc((size_t)nbuk*4 + 256);
  int*   bcnt  = (int*)  alloc((size_t)nbuk*4);
  int*   cntm  = (int*)  alloc((size_t)nbuk*NPB*4);
  int*   basem = (int*)  alloc((size_t)nbuk*NPB*4);
  u32*   ebuf  = (u32*)  alloc((size_t)nbuk*BCAP*4);
  int*   colx  = (int*)  alloc(((size_t)E + 4*(size_t)n)*4 + 256);
  u16*   T     = (u16*)  alloc((size_t)(n+1)*128*2);   // +1 zero pad-row
  u16*   Ws    = (u16*)  alloc((size_t)3*128*128*2);   // 3 layers pre-shuffled
  float* bc    = (float*)alloc((size_t)64*4);
  u16*   Wcs   = (u16*)  alloc((size_t)12*64*8*2);

  k_detect<<<1, 256, 0, stream>>>((const u16*)x, (const u32*)ei, flags, T, n);
  k_shufW3<<<96, 64, 0, stream>>>(W1, W2, W3, Ws, flags);
  k_partA <<<NPB, 256, 0, stream>>>(ei, E, n, cntm, flags, nbuk);
  k_scanBK<<<nbuk, NPB, 0, stream>>>(cntm, basem, bcnt);
  k_partC <<<NPB, 256, 0, stream>>>(ei, E, n, basem, ebuf, flags, nbuk);
  k_bdeg  <<<nbuk, 256, 0, stream>>>(bcnt, ebuf, deg, bksum, n);
  k_scanBkt<<<1, 512, 0, stream>>>(bksum, bkbase, rowp, nbuk, n);
  k_bfill <<<nbuk, 256, 0, stream>>>(bcnt, ebuf, deg, bkbase, rowp, dis, colx, n);
  k_wc    <<<48, 128, 0, stream>>>(mpW1, mpb1, mpW2, mpb2, Wcs, bc, flags);

  int nTiles = (n + 15) / 16;
  int gG = (nTiles + 3) / 4;
  int gA = (n + 15) / 16;    // 16 nodes per block (4 per wave)

  // layer 0
  k_gemm <<<gG, 256, 0, stream>>>(x, 1, Ws, dis, T, nTiles, flags);
  k_agg<0><<<gA, 256, 0, stream>>>(T, rowp, colx, dis, b1, ln1g, ln1b, Hbuf, n, flags);
  // layer 1
  k_gemm <<<gG, 256, 0, stream>>>(Hbuf, 0, Ws + (size_t)128*128, dis, T, nTiles, flags);
  k_agg<0><<<gA, 256, 0, stream>>>(T, rowp, colx, dis, b2, ln2g, ln2b, Hbuf, n, flags);
  // layer 2: emb -> d_out
  k_gemm <<<gG, 256, 0, stream>>>(Hbuf, 0, Ws + (size_t)2*128*128, dis, T, nTiles, flags);
  k_agg<1><<<gA, 256, 0, stream>>>(T, rowp, colx, dis, b3, nullptr, nullptr, d_out, n, flags);
  // post_mp collapsed + log_softmax (MFMA)
  k_logitsM<<<gG, 256, 0, stream>>>(Wcs, bc, d_out, n, flags);
}